// Round 2
// baseline (109.340 us; speedup 1.0000x reference)
//
#include <hip/hip_runtime.h>
#include <hip/hip_bf16.h>
#include <stdint.h>

// ---------------------------------------------------------------------------
// Head: out = softmax((x Wq)(x Wk)^T / 8) (x Wv)
// B=8, T=2048, C=512, D=64.  ALL I/O FP32; internals bf16 MFMA + fp32 accum.
//
// R10: attn 64-q-row blocks (4 q-tiles, 512 thr / 8 waves, keys split
// 8-way). Every K/V fragment now serves 4 q-tiles -> KV L2 traffic halves
// again: 256 blocks x 512KB = 128MB (was 256MB). S computed per q-tile
// PAIR sequentially to bound VGPR (~200 peak); launch_bounds(512,2) caps
// at 256 so the 8-wave block always fits (1 block/CU, 2 waves/SIMD = same
// occupancy as R8/R9). pt (136KB) union-overlaid with obuf (68KB) after a
// barrier; two-stage 8->4->1 partial-O reduction.
// proj/wt unchanged from R9 (proj is ~2us off its HBM floor).
// Keep: frag-order layouts, no-max softmax, XCD batch swizzle.
//
// MFMA 16x16x32 bf16 fragment maps (gfx950, m89/m91-verified):
//   A: lane holds A[m=lane&15][k=quad*8+j]   (quad=lane>>4, j=0..7)
//   B: lane holds B[k=quad*8+j][n=lane&15]
//   D: lane holds D[row=quad*4+r][col=lane&15] (r=reg 0..3)
//
// Fragment-order chunk layouts (16B chunks, chunk's 8 elems = j=0..7):
//   xs (LDS): chunk[db*16 + (tok ^ (db&7))] = x[tt*16+tok][db*8+j], db=ks*4+quad
//   wt2: chunk[(((w*4+mt)*16+ks)*4+quad)*16+c] = W_w[ks*32+quad*8+j][mt*16+c]
//   kg2: chunk[b*16384 + ((g*2+h)*4+quad)*16+c] = K[b][g*16+c][h*32+quad*8+j]
//   vg2: chunk[b*16384 + ((s*4+mt)*4+quad)*16+c] = V[b][s*32+quad*8+j][mt*16+c]
// ---------------------------------------------------------------------------

typedef short bf16x8 __attribute__((ext_vector_type(8)));
typedef float f32x4 __attribute__((ext_vector_type(4)));

#define MFMA_BF16 __builtin_amdgcn_mfma_f32_16x16x32_bf16

__device__ __forceinline__ unsigned int pk2(float a, float b) {
    __hip_bfloat162 h = __float22bfloat162_rn(float2{a, b});   // v_cvt_pk_bf16_f32
    union { __hip_bfloat162 h; unsigned int u; } r; r.h = h;
    return r.u;
}

__device__ __forceinline__ uint2 pack4_bf16(float a, float b, float c, float d) {
    uint2 r; r.x = pk2(a, b); r.y = pk2(c, d); return r;
}

__device__ __forceinline__ bf16x8 cvt8(f32x4 a, f32x4 b) {
    union { bf16x8 v; unsigned int u[4]; } r;
    r.u[0] = pk2(a[0], a[1]); r.u[1] = pk2(a[2], a[3]);
    r.u[2] = pk2(b[0], b[1]); r.u[3] = pk2(b[2], b[3]);
    return r.v;
}

__device__ __forceinline__ unsigned short bf1(float a) {
    __hip_bfloat16 h = __float2bfloat16(a);
    union { __hip_bfloat16 h; unsigned short u; } r; r.h = h;
    return r.u;
}

// ---------------------------------------------------------------------------
// Kernel 0: weight fragments only (48 blocks). Unchanged.
// ---------------------------------------------------------------------------
__global__ void wt_kernel(const float* __restrict__ Wq,
                          const float* __restrict__ Wk,
                          const float* __restrict__ Wv,
                          unsigned short* __restrict__ wt2)
{
    int id = blockIdx.x * 256 + threadIdx.x;      // 12288 = 3*4*16*4*16
    int c    = id & 15;
    int quad = (id >> 4) & 3;
    int ks   = (id >> 6) & 15;
    int mt   = (id >> 10) & 3;
    int w    = id >> 12;
    const float* src = (w == 0) ? Wq : ((w == 1) ? Wk : Wv);
    const int n  = mt * 16 + c;
    const int k0 = ks * 32 + quad * 8;
    unsigned short* dst = wt2 + (size_t)id * 8;
    #pragma unroll
    for (int j = 0; j < 8; j++)
        dst[j] = bf1(src[(size_t)(k0 + j) * 64 + n]);
}

// ---------------------------------------------------------------------------
// Kernel 1: fused convert + projections. Unchanged from R9.
// 1024 blocks x 256 threads; LDS 16KB.
// ---------------------------------------------------------------------------
__global__ __launch_bounds__(256, 1) void proj_kernel(
    const float* __restrict__ x, const unsigned short* __restrict__ wt2,
    unsigned short* __restrict__ qg, unsigned short* __restrict__ kg2,
    unsigned short* __restrict__ vg2)
{
    __shared__ unsigned short xs[8192];           // 16 KiB, 1024 16B chunks

    const int tid  = threadIdx.x;
    const int lane = tid & 63;
    const int wave = tid >> 6;
    const int c    = lane & 15;
    const int quad = lane >> 4;
    const int tt   = blockIdx.x;                  // token tile 0..1023
    const int t0   = tt * 16;

    // ---- stage x tile (16 tok x 512 C fp32 = 32KB) -> frag-order LDS ----
    const float* xb = x + (size_t)tt * 8192;
    #pragma unroll
    for (int t = 0; t < 4; t++) {
        int i = t * 256 + tid;                    // float8 index 0..1023
        f32x4 a = *(const f32x4*)(xb + (size_t)i * 8);
        f32x4 b = *(const f32x4*)(xb + (size_t)i * 8 + 4);
        int tok = i >> 6;                         // token_local (frag col)
        int db  = i & 63;                         // = ks*4+quad (C block)
        *(bf16x8*)(xs + db * 128 + ((tok ^ (db & 7)) * 8)) = cvt8(a, b);
    }
    __syncthreads();

    // ---- GEMM: this wave owns frags f = wave*3 .. wave*3+2 ----
    f32x4 acc[3];
    #pragma unroll
    for (int r = 0; r < 3; r++) acc[r] = f32x4{0.f, 0.f, 0.f, 0.f};

    const int fbase = wave * 3;
    #pragma unroll 4
    for (int ks = 0; ks < 16; ks++) {
        bf16x8 xf = *(const bf16x8*)(
            xs + ks * 512 + quad * 128 + ((c ^ ((ks * 4 + quad) & 7)) * 8));
        #pragma unroll
        for (int r = 0; r < 3; r++) {
            int f = fbase + r;
            bf16x8 wa = *(const bf16x8*)(wt2 + ((size_t)(f * 16 + ks) * 64 + lane) * 8);
            acc[r] = MFMA_BF16(wa, xf, acc[r], 0, 0, 0);
        }
    }

    // ---- epilogue: per-frag store ----
    const int b  = t0 >> 11;             // batch
    const int tb = t0 & 2047;            // batch-local tile base

    #pragma unroll
    for (int r = 0; r < 3; r++) {
        const int f  = fbase + r;
        const int w  = f >> 2;           // matrix: 0:q 1:k 2:v
        const int mt = f & 3;
        if (w == 0) {
            unsigned short* base = qg + (size_t)(t0 + c) * 64;
            *(uint2*)(base + mt * 16 + quad * 4) =
                pack4_bf16(acc[r][0], acc[r][1], acc[r][2], acc[r][3]);
        } else if (w == 1) {
            const int g  = tb >> 4;
            const int h  = mt >> 1;
            const int qk = (mt & 1) * 2 + (quad >> 1);
            size_t chunk = (size_t)b * 16384 + ((size_t)(g * 2 + h) * 4 + qk) * 16 + c;
            *(uint2*)(kg2 + chunk * 8 + (quad & 1) * 4) =
                pack4_bf16(acc[r][0], acc[r][1], acc[r][2], acc[r][3]);
        } else {
            const int tk = tb + c;
            const int s  = tk >> 5;
            const int qv = (tk >> 3) & 3;
            const int j  = tk & 7;
            size_t chunk = (size_t)b * 16384 + ((size_t)(s * 4 + mt) * 4 + qv) * 16 + quad * 4;
            unsigned short* dst = vg2 + chunk * 8 + j;
            dst[0]  = bf1(acc[r][0]);
            dst[8]  = bf1(acc[r][1]);
            dst[16] = bf1(acc[r][2]);
            dst[24] = bf1(acc[r][3]);
        }
    }
}

// ---------------------------------------------------------------------------
// Kernel 2: flash attention, 64 q-rows per block (4 q-tiles), 8 waves
// splitting the 2048 keys 8 ways (2 x 128-key tiles each). K/V frags
// loaded once per block serve all 4 q-tiles. S computed per q-tile PAIR
// sequentially (bounds VGPR); no-max softmax; l reduced once per tile.
// Epilogue: two-stage 8-partial reduction in LDS (obuf overlays pt).
// 256 blocks x 512 threads; LDS ~138KB -> 1 block/CU -> 8 waves/CU.
// ---------------------------------------------------------------------------
__global__ __launch_bounds__(512, 2) void attn_kernel(
    const unsigned short* __restrict__ qg, const unsigned short* __restrict__ kg2,
    const unsigned short* __restrict__ vg2, float* __restrict__ out)
{
    // pt: [wave][qtile][q=16][key=136]  (136 stride de-conflicts)
    __shared__ __align__(16) unsigned short pt[8][4][16 * 136];  // 139,264 B
    __shared__ float lbuf[8][4][16];                             // 2 KiB
    // obuf overlays pt AFTER the post-loop barrier: [part=4][qt=4][q=16][d=68]
    float* obase = reinterpret_cast<float*>(&pt[0][0][0]);       // 69,632 B used

    const int lane = threadIdx.x & 63;
    const int wave = threadIdx.x >> 6;           // 0..7
    const int c    = lane & 15;
    const int quad = lane >> 4;
    const int b    = blockIdx.x & 7;             // batch -> XCD (L2 locality)
    const int g    = blockIdx.x >> 3;            // 64-row group (0..31)
    const int tb   = b * 2048 + g * 64;          // block q base

    unsigned short* ptw = &pt[wave][0][0];
    const unsigned short* kbase = kg2 + ((size_t)b * 16384 + lane) * 8;
    const unsigned short* vbase = vg2 + ((size_t)b * 16384 + lane) * 8;

    // Q frags for 4 q-tiles
    bf16x8 qA0 = *(const bf16x8*)(qg + (size_t)(tb + c) * 64 + quad * 8);
    bf16x8 qA1 = *(const bf16x8*)(qg + (size_t)(tb + c) * 64 + 32 + quad * 8);
    bf16x8 qB0 = *(const bf16x8*)(qg + (size_t)(tb + 16 + c) * 64 + quad * 8);
    bf16x8 qB1 = *(const bf16x8*)(qg + (size_t)(tb + 16 + c) * 64 + 32 + quad * 8);
    bf16x8 qC0 = *(const bf16x8*)(qg + (size_t)(tb + 32 + c) * 64 + quad * 8);
    bf16x8 qC1 = *(const bf16x8*)(qg + (size_t)(tb + 32 + c) * 64 + 32 + quad * 8);
    bf16x8 qD0 = *(const bf16x8*)(qg + (size_t)(tb + 48 + c) * 64 + quad * 8);
    bf16x8 qD1 = *(const bf16x8*)(qg + (size_t)(tb + 48 + c) * 64 + 32 + quad * 8);

    f32x4 oa0 = {0,0,0,0}, oa1 = {0,0,0,0}, oa2 = {0,0,0,0}, oa3 = {0,0,0,0};
    f32x4 ob0 = {0,0,0,0}, ob1 = {0,0,0,0}, ob2 = {0,0,0,0}, ob3 = {0,0,0,0};
    f32x4 oc0 = {0,0,0,0}, oc1 = {0,0,0,0}, oc2 = {0,0,0,0}, oc3 = {0,0,0,0};
    f32x4 od0 = {0,0,0,0}, od1 = {0,0,0,0}, od2 = {0,0,0,0}, od3 = {0,0,0,0};
    f32x4 laccA = {0,0,0,0}, laccB = {0,0,0,0};
    f32x4 laccC = {0,0,0,0}, laccD = {0,0,0,0};
    const float cexp = 0.18033688011112042f;   // log2(e)/8  (scores = raw/8)

    for (int kt = wave * 2; kt < wave * 2 + 2; kt++) {
        const int key0 = kt * 128;
        const int g0   = key0 >> 4;              // 16-key group base
        const int s0   = key0 >> 5;              // 32-key block base
        const f32x4 z = {0,0,0,0};

        // ---- pair 1: S^T = K·Q^T for q-tiles A,B ----
        f32x4 stA[8], stB[8];
        #pragma unroll
        for (int mt = 0; mt < 8; mt++) {
            bf16x8 k0 = *(const bf16x8*)(kbase + (size_t)((g0 + mt) * 2    ) * 64 * 8);
            bf16x8 k1 = *(const bf16x8*)(kbase + (size_t)((g0 + mt) * 2 + 1) * 64 * 8);
            stA[mt] = MFMA_BF16(k0, qA0, z, 0, 0, 0);
            stA[mt] = MFMA_BF16(k1, qA1, stA[mt], 0, 0, 0);
            stB[mt] = MFMA_BF16(k0, qB0, z, 0, 0, 0);
            stB[mt] = MFMA_BF16(k1, qB1, stB[mt], 0, 0, 0);
        }

        // ---- exp pair 1 -> pt tiles 0,1 (hides pair-2 K load latency) ----
        asm volatile("" ::: "memory");
        #pragma unroll
        for (int mt = 0; mt < 8; mt++) {
            float p0 = __builtin_amdgcn_exp2f(stA[mt][0] * cexp);
            float p1 = __builtin_amdgcn_exp2f(stA[mt][1] * cexp);
            float p2 = __builtin_amdgcn_exp2f(stA[mt][2] * cexp);
            float p3 = __builtin_amdgcn_exp2f(stA[mt][3] * cexp);
            laccA[0] += p0; laccA[1] += p1; laccA[2] += p2; laccA[3] += p3;
            *(uint2*)(ptw + c * 136 + mt * 16 + quad * 4) = pack4_bf16(p0, p1, p2, p3);
        }
        #pragma unroll
        for (int mt = 0; mt < 8; mt++) {
            float p0 = __builtin_amdgcn_exp2f(stB[mt][0] * cexp);
            float p1 = __builtin_amdgcn_exp2f(stB[mt][1] * cexp);
            float p2 = __builtin_amdgcn_exp2f(stB[mt][2] * cexp);
            float p3 = __builtin_amdgcn_exp2f(stB[mt][3] * cexp);
            laccB[0] += p0; laccB[1] += p1; laccB[2] += p2; laccB[3] += p3;
            *(uint2*)(ptw + 2176 + c * 136 + mt * 16 + quad * 4) = pack4_bf16(p0, p1, p2, p3);
        }
        asm volatile("" ::: "memory");

        // ---- pair 2: S^T for q-tiles C,D (K frags re-read, L2-hot) ----
        f32x4 stC[8], stD[8];
        #pragma unroll
        for (int mt = 0; mt < 8; mt++) {
            bf16x8 k0 = *(const bf16x8*)(kbase + (size_t)((g0 + mt) * 2    ) * 64 * 8);
            bf16x8 k1 = *(const bf16x8*)(kbase + (size_t)((g0 + mt) * 2 + 1) * 64 * 8);
            stC[mt] = MFMA_BF16(k0, qC0, z, 0, 0, 0);
            stC[mt] = MFMA_BF16(k1, qC1, stC[mt], 0, 0, 0);
            stD[mt] = MFMA_BF16(k0, qD0, z, 0, 0, 0);
            stD[mt] = MFMA_BF16(k1, qD1, stD[mt], 0, 0, 0);
        }

        // ---- preload V ks=0,1 so latency hides under exp section ----
        bf16x8 va[2][4];
        #pragma unroll
        for (int mt = 0; mt < 4; mt++) {
            va[0][mt] = *(const bf16x8*)(vbase + (size_t)((s0    ) * 4 + mt) * 64 * 8);
            va[1][mt] = *(const bf16x8*)(vbase + (size_t)((s0 + 1) * 4 + mt) * 64 * 8);
        }

        // ---- exp pair 2 -> pt tiles 2,3 ----
        asm volatile("" ::: "memory");
        #pragma unroll
        for (int mt = 0; mt < 8; mt++) {
            float p0 = __builtin_amdgcn_exp2f(stC[mt][0] * cexp);
            float p1 = __builtin_amdgcn_exp2f(stC[mt][1] * cexp);
            float p2 = __builtin_amdgcn_exp2f(stC[mt][2] * cexp);
            float p3 = __builtin_amdgcn_exp2f(stC[mt][3] * cexp);
            laccC[0] += p0; laccC[1] += p1; laccC[2] += p2; laccC[3] += p3;
            *(uint2*)(ptw + 2 * 2176 + c * 136 + mt * 16 + quad * 4) = pack4_bf16(p0, p1, p2, p3);
        }
        #pragma unroll
        for (int mt = 0; mt < 8; mt++) {
            float p0 = __builtin_amdgcn_exp2f(stD[mt][0] * cexp);
            float p1 = __builtin_amdgcn_exp2f(stD[mt][1] * cexp);
            float p2 = __builtin_amdgcn_exp2f(stD[mt][2] * cexp);
            float p3 = __builtin_amdgcn_exp2f(stD[mt][3] * cexp);
            laccD[0] += p0; laccD[1] += p1; laccD[2] += p2; laccD[3] += p3;
            *(uint2*)(ptw + 3 * 2176 + c * 136 + mt * 16 + quad * 4) = pack4_bf16(p0, p1, p2, p3);
        }
        asm volatile("" ::: "memory");

        // ---- O^T += V^T·P^T for all 4 q-tiles; V frags loaded once ----
        #pragma unroll
        for (int ks = 0; ks < 4; ks++) {
            bf16x8 pbA = *(const bf16x8*)(ptw            + c * 136 + ks * 32 + quad * 8);
            bf16x8 pbB = *(const bf16x8*)(ptw +     2176 + c * 136 + ks * 32 + quad * 8);
            bf16x8 pbC = *(const bf16x8*)(ptw + 2 * 2176 + c * 136 + ks * 32 + quad * 8);
            bf16x8 pbD = *(const bf16x8*)(ptw + 3 * 2176 + c * 136 + ks * 32 + quad * 8);
            bf16x8 v0 = va[ks & 1][0], v1 = va[ks & 1][1];
            bf16x8 v2 = va[ks & 1][2], v3 = va[ks & 1][3];
            if (ks < 2) {
                #pragma unroll
                for (int mt = 0; mt < 4; mt++)
                    va[ks & 1][mt] =
                        *(const bf16x8*)(vbase + (size_t)((s0 + ks + 2) * 4 + mt) * 64 * 8);
            }
            oa0 = MFMA_BF16(v0, pbA, oa0, 0, 0, 0);
            oa1 = MFMA_BF16(v1, pbA, oa1, 0, 0, 0);
            oa2 = MFMA_BF16(v2, pbA, oa2, 0, 0, 0);
            oa3 = MFMA_BF16(v3, pbA, oa3, 0, 0, 0);
            ob0 = MFMA_BF16(v0, pbB, ob0, 0, 0, 0);
            ob1 = MFMA_BF16(v1, pbB, ob1, 0, 0, 0);
            ob2 = MFMA_BF16(v2, pbB, ob2, 0, 0, 0);
            ob3 = MFMA_BF16(v3, pbB, ob3, 0, 0, 0);
            oc0 = MFMA_BF16(v0, pbC, oc0, 0, 0, 0);
            oc1 = MFMA_BF16(v1, pbC, oc1, 0, 0, 0);
            oc2 = MFMA_BF16(v2, pbC, oc2, 0, 0, 0);
            oc3 = MFMA_BF16(v3, pbC, oc3, 0, 0, 0);
            od0 = MFMA_BF16(v0, pbD, od0, 0, 0, 0);
            od1 = MFMA_BF16(v1, pbD, od1, 0, 0, 0);
            od2 = MFMA_BF16(v2, pbD, od2, 0, 0, 0);
            od3 = MFMA_BF16(v3, pbD, od3, 0, 0, 0);
        }
        asm volatile("" ::: "memory");
    }

    // ---- one l reduction per wave per q-tile ----
    float lA = (laccA[0] + laccA[1]) + (laccA[2] + laccA[3]);
    lA += __shfl_xor(lA, 16); lA += __shfl_xor(lA, 32);
    float lB = (laccB[0] + laccB[1]) + (laccB[2] + laccB[3]);
    lB += __shfl_xor(lB, 16); lB += __shfl_xor(lB, 32);
    float lC = (laccC[0] + laccC[1]) + (laccC[2] + laccC[3]);
    lC += __shfl_xor(lC, 16); lC += __shfl_xor(lC, 32);
    float lD = (laccD[0] + laccD[1]) + (laccD[2] + laccD[3]);
    lD += __shfl_xor(lD, 16); lD += __shfl_xor(lD, 32);
    if (quad == 0) {
        lbuf[wave][0][c] = lA; lbuf[wave][1][c] = lB;
        lbuf[wave][2][c] = lC; lbuf[wave][3][c] = lD;
    }

    // ---- all waves done with pt before obuf overlays it ----
    __syncthreads();

    // obuf(p,qt,r,d) = obase[((p*4+qt)*16 + r)*68 + d]
    if (wave < 4) {
        float* o0 = obase + ((size_t)(wave * 4 + 0) * 16 + c) * 68 + quad * 4;
        float* o1 = obase + ((size_t)(wave * 4 + 1) * 16 + c) * 68 + quad * 4;
        float* o2 = obase + ((size_t)(wave * 4 + 2) * 16 + c) * 68 + quad * 4;
        float* o3 = obase + ((size_t)(wave * 4 + 3) * 16 + c) * 68 + quad * 4;
        *(f32x4*)(o0 +  0) = oa0; *(f32x4*)(o0 + 16) = oa1;
        *(f32x4*)(o0 + 32) = oa2; *(f32x4*)(o0 + 48) = oa3;
        *(f32x4*)(o1 +  0) = ob0; *(f32x4*)(o1 + 16) = ob1;
        *(f32x4*)(o1 + 32) = ob2; *(f32x4*)(o1 + 48) = ob3;
        *(f32x4*)(o2 +  0) = oc0; *(f32x4*)(o2 + 16) = oc1;
        *(f32x4*)(o2 + 32) = oc2; *(f32x4*)(o2 + 48) = oc3;
        *(f32x4*)(o3 +  0) = od0; *(f32x4*)(o3 + 16) = od1;
        *(f32x4*)(o3 + 32) = od2; *(f32x4*)(o3 + 48) = od3;
    }
    __syncthreads();

    if (wave >= 4) {
        const int p = wave - 4;
        float* o0 = obase + ((size_t)(p * 4 + 0) * 16 + c) * 68 + quad * 4;
        float* o1 = obase + ((size_t)(p * 4 + 1) * 16 + c) * 68 + quad * 4;
        float* o2 = obase + ((size_t)(p * 4 + 2) * 16 + c) * 68 + quad * 4;
        float* o3 = obase + ((size_t)(p * 4 + 3) * 16 + c) * 68 + quad * 4;
        #define ADDSTORE(ptr, off, reg) { f32x4 t = *(f32x4*)((ptr) + (off)); \
            t[0] += reg[0]; t[1] += reg[1]; t[2] += reg[2]; t[3] += reg[3];   \
            *(f32x4*)((ptr) + (off)) = t; }
        ADDSTORE(o0,  0, oa0); ADDSTORE(o0, 16, oa1);
        ADDSTORE(o0, 32, oa2); ADDSTORE(o0, 48, oa3);
        ADDSTORE(o1,  0, ob0); ADDSTORE(o1, 16, ob1);
        ADDSTORE(o1, 32, ob2); ADDSTORE(o1, 48, ob3);
        ADDSTORE(o2,  0, oc0); ADDSTORE(o2, 16, oc1);
        ADDSTORE(o2, 32, oc2); ADDSTORE(o2, 48, oc3);
        ADDSTORE(o3,  0, od0); ADDSTORE(o3, 16, od1);
        ADDSTORE(o3, 32, od2); ADDSTORE(o3, 48, od3);
        #undef ADDSTORE
    }
    __syncthreads();

    // ---- combine 4 partials; 512 thr x 8 floats, coalesced ----
    const int tid = threadIdx.x;
    const int row = tid >> 3;                    // block-local q row (0..63)
    const int d0  = (tid & 7) * 8;               // d base (0..56)
    const int qt  = row >> 4;
    const int r   = row & 15;
    float L = 0.f;
    #pragma unroll
    for (int w = 0; w < 8; w++) L += lbuf[w][qt][r];
    const float rl = 1.f / L;
    f32x4 Oa = {0,0,0,0}, Ob = {0,0,0,0};
    #pragma unroll
    for (int p = 0; p < 4; p++) {
        const float* src = obase + ((size_t)(p * 4 + qt) * 16 + r) * 68 + d0;
        f32x4 a   = *(const f32x4*)(src);
        f32x4 bfr = *(const f32x4*)(src + 4);
        Oa[0] += a[0]; Oa[1] += a[1]; Oa[2] += a[2]; Oa[3] += a[3];
        Ob[0] += bfr[0]; Ob[1] += bfr[1]; Ob[2] += bfr[2]; Ob[3] += bfr[3];
    }
    Oa[0] *= rl; Oa[1] *= rl; Oa[2] *= rl; Oa[3] *= rl;
    Ob[0] *= rl; Ob[1] *= rl; Ob[2] *= rl; Ob[3] *= rl;
    float* op = out + (size_t)(tb + row) * 64 + d0;
    *(f32x4*)op       = Oa;
    *(f32x4*)(op + 4) = Ob;
}

// ---------------------------------------------------------------------------
extern "C" void kernel_launch(void* const* d_in, const int* in_sizes, int n_in,
                              void* d_out, int out_size, void* d_ws, size_t ws_size,
                              hipStream_t stream)
{
    const float* x  = (const float*)d_in[0];
    const float* Wk = (const float*)d_in[1];
    const float* Wq = (const float*)d_in[2];
    const float* Wv = (const float*)d_in[3];
    float* out = (float*)d_out;

    char* ws = (char*)d_ws;
    unsigned short* qg  = (unsigned short*)(ws);                  // 2 MiB
    unsigned short* kg2 = (unsigned short*)(ws + (2u << 20));     // 2 MiB
    unsigned short* vg2 = (unsigned short*)(ws + (4u << 20));     // 2 MiB
    unsigned short* wt2 = (unsigned short*)(ws + (6u << 20));     // 192 KiB

    hipLaunchKernelGGL(wt_kernel,   dim3(48),   dim3(256), 0, stream,
                       Wq, Wk, Wv, wt2);
    hipLaunchKernelGGL(proj_kernel, dim3(1024), dim3(256), 0, stream,
                       x, wt2, qg, kg2, vg2);
    hipLaunchKernelGGL(attn_kernel, dim3(256),  dim3(512), 0, stream,
                       qg, kg2, vg2, out);
}

// Round 3
// 106.325 us; speedup vs baseline: 1.0284x; 1.0284x over previous
//
#include <hip/hip_runtime.h>
#include <hip/hip_bf16.h>
#include <stdint.h>

// ---------------------------------------------------------------------------
// Head: out = softmax((x Wq)(x Wk)^T / 8) (x Wv)
// B=8, T=2048, C=512, D=64.  ALL I/O FP32; internals bf16 MFMA + fp32 accum.
//
// R11: proj 64-token blocks. R10 (attn KV-traffic halving) was dead
// neutral -> attn is latency-hidden, not L2-bound; kept as-is. Remaining
// visible waste: proj weight re-reads (1024 blocks x 196KB wt2 = 201MB L2,
// ~5.8us of L2 time racing the 5.6us HBM x-stream). 64-token tiles cut
// weight traffic 4x to 50MB: per-ks weight frags feed 4 token-subtiles
// (12 MFMA / 7 loads vs 3 / 4). 256 blocks, 64KB LDS, 2 blocks/CU.
// wt/attn unchanged from R10 for clean A/B.
// Keep: frag-order layouts, no-max softmax, XCD batch swizzle,
// launch_bounds (R3: min-waves=4 caused 96MB scratch spill).
//
// MFMA 16x16x32 bf16 fragment maps (gfx950, m89/m91-verified):
//   A: lane holds A[m=lane&15][k=quad*8+j]   (quad=lane>>4, j=0..7)
//   B: lane holds B[k=quad*8+j][n=lane&15]
//   D: lane holds D[row=quad*4+r][col=lane&15] (r=reg 0..3)
//
// Fragment-order chunk layouts (16B chunks, chunk's 8 elems = j=0..7):
//   xs (LDS): chunk[db*64 + (tok ^ (db&7))] = x[tt*64+tok][db*8+j], db=ks*4+quad
//   wt2: chunk[(((w*4+mt)*16+ks)*4+quad)*16+c] = W_w[ks*32+quad*8+j][mt*16+c]
//   kg2: chunk[b*16384 + ((g*2+h)*4+quad)*16+c] = K[b][g*16+c][h*32+quad*8+j]
//   vg2: chunk[b*16384 + ((s*4+mt)*4+quad)*16+c] = V[b][s*32+quad*8+j][mt*16+c]
// ---------------------------------------------------------------------------

typedef short bf16x8 __attribute__((ext_vector_type(8)));
typedef float f32x4 __attribute__((ext_vector_type(4)));

#define MFMA_BF16 __builtin_amdgcn_mfma_f32_16x16x32_bf16

__device__ __forceinline__ unsigned int pk2(float a, float b) {
    __hip_bfloat162 h = __float22bfloat162_rn(float2{a, b});   // v_cvt_pk_bf16_f32
    union { __hip_bfloat162 h; unsigned int u; } r; r.h = h;
    return r.u;
}

__device__ __forceinline__ uint2 pack4_bf16(float a, float b, float c, float d) {
    uint2 r; r.x = pk2(a, b); r.y = pk2(c, d); return r;
}

__device__ __forceinline__ bf16x8 cvt8(f32x4 a, f32x4 b) {
    union { bf16x8 v; unsigned int u[4]; } r;
    r.u[0] = pk2(a[0], a[1]); r.u[1] = pk2(a[2], a[3]);
    r.u[2] = pk2(b[0], b[1]); r.u[3] = pk2(b[2], b[3]);
    return r.v;
}

__device__ __forceinline__ unsigned short bf1(float a) {
    __hip_bfloat16 h = __float2bfloat16(a);
    union { __hip_bfloat16 h; unsigned short u; } r; r.h = h;
    return r.u;
}

// ---------------------------------------------------------------------------
// Kernel 0: weight fragments only (48 blocks). Unchanged.
// ---------------------------------------------------------------------------
__global__ void wt_kernel(const float* __restrict__ Wq,
                          const float* __restrict__ Wk,
                          const float* __restrict__ Wv,
                          unsigned short* __restrict__ wt2)
{
    int id = blockIdx.x * 256 + threadIdx.x;      // 12288 = 3*4*16*4*16
    int c    = id & 15;
    int quad = (id >> 4) & 3;
    int ks   = (id >> 6) & 15;
    int mt   = (id >> 10) & 3;
    int w    = id >> 12;
    const float* src = (w == 0) ? Wq : ((w == 1) ? Wk : Wv);
    const int n  = mt * 16 + c;
    const int k0 = ks * 32 + quad * 8;
    unsigned short* dst = wt2 + (size_t)id * 8;
    #pragma unroll
    for (int j = 0; j < 8; j++)
        dst[j] = bf1(src[(size_t)(k0 + j) * 64 + n]);
}

// ---------------------------------------------------------------------------
// Kernel 1: fused convert + projections, 64-token blocks.
//   Stage: 16 f32x4-pair loads/thread, fully coalesced (128KB contiguous
//   per block); bf16 fragment order in LDS with XOR slot swizzle
//   (slot = tok ^ (db&7): stays within the 16-token subtile; writes 8-way
//   benign, per-subtile reads are the same permuted 256B run as R9).
//   GEMM: wave owns frags f=wave*3..+2 across 4 token-subtiles; per ks,
//   3 weight loads + 4 LDS reads feed 12 MFMAs (was 3 loads + 1 read -> 3).
//   Weight L2 traffic: 256 blocks x 196KB = 50MB (was 201MB).
// 256 blocks x 256 threads; LDS 64KB -> 2 blocks/CU.
// ---------------------------------------------------------------------------
__global__ __launch_bounds__(256, 1) void proj_kernel(
    const float* __restrict__ x, const unsigned short* __restrict__ wt2,
    unsigned short* __restrict__ qg, unsigned short* __restrict__ kg2,
    unsigned short* __restrict__ vg2)
{
    __shared__ unsigned short xs[32768];          // 64 KiB, 4096 16B chunks

    const int tid  = threadIdx.x;
    const int lane = tid & 63;
    const int wave = tid >> 6;
    const int c    = lane & 15;
    const int quad = lane >> 4;
    const int tt   = blockIdx.x;                  // 64-token tile 0..255
    const int t0   = tt * 64;

    // ---- stage x tile (64 tok x 512 C fp32 = 128KB) -> frag-order LDS ----
    const float* xb = x + (size_t)tt * 32768;
    #pragma unroll
    for (int t = 0; t < 16; t++) {
        int i = t * 256 + tid;                    // float8 index 0..4095
        f32x4 a = *(const f32x4*)(xb + (size_t)i * 8);
        f32x4 b = *(const f32x4*)(xb + (size_t)i * 8 + 4);
        int tok = i >> 6;                         // token_local 0..63
        int db  = i & 63;                         // = ks*4+quad (C block)
        *(bf16x8*)(xs + ((size_t)db * 64 + (tok ^ (db & 7))) * 8) = cvt8(a, b);
    }
    __syncthreads();

    // ---- GEMM: wave owns frags f = wave*3..+2, all 4 token-subtiles ----
    f32x4 acc[3][4];
    #pragma unroll
    for (int r = 0; r < 3; r++)
        #pragma unroll
        for (int st = 0; st < 4; st++) acc[r][st] = f32x4{0.f, 0.f, 0.f, 0.f};

    const int fbase = wave * 3;
    #pragma unroll 2
    for (int ks = 0; ks < 16; ks++) {
        bf16x8 wa[3];
        #pragma unroll
        for (int r = 0; r < 3; r++)
            wa[r] = *(const bf16x8*)(
                wt2 + ((size_t)((fbase + r) * 16 + ks) * 64 + lane) * 8);
        const int sw = c ^ ((ks & 1) * 4 + quad);     // (ks*4+quad)&7
        const unsigned short* xrow = xs + ((size_t)(ks * 4 + quad) * 64 + sw) * 8;
        #pragma unroll
        for (int st = 0; st < 4; st++) {
            bf16x8 xf = *(const bf16x8*)(xrow + (size_t)st * 16 * 8);
            #pragma unroll
            for (int r = 0; r < 3; r++)
                acc[r][st] = MFMA_BF16(wa[r], xf, acc[r][st], 0, 0, 0);
        }
    }

    // ---- epilogue: per-frag, per-subtile store ----
    const int b = t0 >> 11;              // batch (constant per block)

    #pragma unroll
    for (int r = 0; r < 3; r++) {
        const int f  = fbase + r;
        const int w  = f >> 2;           // matrix: 0:q 1:k 2:v
        const int mt = f & 3;
        #pragma unroll
        for (int st = 0; st < 4; st++) {
            const int ts = t0 + st * 16;         // subtile global token base
            const int tb = ts & 2047;            // batch-local tile base
            if (w == 0) {
                unsigned short* base = qg + (size_t)(ts + c) * 64;
                *(uint2*)(base + mt * 16 + quad * 4) =
                    pack4_bf16(acc[r][st][0], acc[r][st][1], acc[r][st][2], acc[r][st][3]);
            } else if (w == 1) {
                const int g  = tb >> 4;
                const int h  = mt >> 1;
                const int qk = (mt & 1) * 2 + (quad >> 1);
                size_t chunk = (size_t)b * 16384 + ((size_t)(g * 2 + h) * 4 + qk) * 16 + c;
                *(uint2*)(kg2 + chunk * 8 + (quad & 1) * 4) =
                    pack4_bf16(acc[r][st][0], acc[r][st][1], acc[r][st][2], acc[r][st][3]);
            } else {
                const int tk = tb + c;
                const int s  = tk >> 5;
                const int qv = (tk >> 3) & 3;
                const int j  = tk & 7;
                size_t chunk = (size_t)b * 16384 + ((size_t)(s * 4 + mt) * 4 + qv) * 16 + quad * 4;
                unsigned short* dst = vg2 + chunk * 8 + j;
                dst[0]  = bf1(acc[r][st][0]);
                dst[8]  = bf1(acc[r][st][1]);
                dst[16] = bf1(acc[r][st][2]);
                dst[24] = bf1(acc[r][st][3]);
            }
        }
    }
}

// ---------------------------------------------------------------------------
// Kernel 2: flash attention, 64 q-rows per block (4 q-tiles), 8 waves
// splitting the 2048 keys 8 ways. Unchanged from R10 (neutral vs R9 but
// traffic-cheaper). 256 blocks x 512 threads; LDS ~138KB -> 1 block/CU.
// ---------------------------------------------------------------------------
__global__ __launch_bounds__(512, 2) void attn_kernel(
    const unsigned short* __restrict__ qg, const unsigned short* __restrict__ kg2,
    const unsigned short* __restrict__ vg2, float* __restrict__ out)
{
    // pt: [wave][qtile][q=16][key=136]  (136 stride de-conflicts)
    __shared__ __align__(16) unsigned short pt[8][4][16 * 136];  // 139,264 B
    __shared__ float lbuf[8][4][16];                             // 2 KiB
    // obuf overlays pt AFTER the post-loop barrier: [part=4][qt=4][q=16][d=68]
    float* obase = reinterpret_cast<float*>(&pt[0][0][0]);       // 69,632 B used

    const int lane = threadIdx.x & 63;
    const int wave = threadIdx.x >> 6;           // 0..7
    const int c    = lane & 15;
    const int quad = lane >> 4;
    const int b    = blockIdx.x & 7;             // batch -> XCD (L2 locality)
    const int g    = blockIdx.x >> 3;            // 64-row group (0..31)
    const int tb   = b * 2048 + g * 64;          // block q base

    unsigned short* ptw = &pt[wave][0][0];
    const unsigned short* kbase = kg2 + ((size_t)b * 16384 + lane) * 8;
    const unsigned short* vbase = vg2 + ((size_t)b * 16384 + lane) * 8;

    // Q frags for 4 q-tiles
    bf16x8 qA0 = *(const bf16x8*)(qg + (size_t)(tb + c) * 64 + quad * 8);
    bf16x8 qA1 = *(const bf16x8*)(qg + (size_t)(tb + c) * 64 + 32 + quad * 8);
    bf16x8 qB0 = *(const bf16x8*)(qg + (size_t)(tb + 16 + c) * 64 + quad * 8);
    bf16x8 qB1 = *(const bf16x8*)(qg + (size_t)(tb + 16 + c) * 64 + 32 + quad * 8);
    bf16x8 qC0 = *(const bf16x8*)(qg + (size_t)(tb + 32 + c) * 64 + quad * 8);
    bf16x8 qC1 = *(const bf16x8*)(qg + (size_t)(tb + 32 + c) * 64 + 32 + quad * 8);
    bf16x8 qD0 = *(const bf16x8*)(qg + (size_t)(tb + 48 + c) * 64 + quad * 8);
    bf16x8 qD1 = *(const bf16x8*)(qg + (size_t)(tb + 48 + c) * 64 + 32 + quad * 8);

    f32x4 oa0 = {0,0,0,0}, oa1 = {0,0,0,0}, oa2 = {0,0,0,0}, oa3 = {0,0,0,0};
    f32x4 ob0 = {0,0,0,0}, ob1 = {0,0,0,0}, ob2 = {0,0,0,0}, ob3 = {0,0,0,0};
    f32x4 oc0 = {0,0,0,0}, oc1 = {0,0,0,0}, oc2 = {0,0,0,0}, oc3 = {0,0,0,0};
    f32x4 od0 = {0,0,0,0}, od1 = {0,0,0,0}, od2 = {0,0,0,0}, od3 = {0,0,0,0};
    f32x4 laccA = {0,0,0,0}, laccB = {0,0,0,0};
    f32x4 laccC = {0,0,0,0}, laccD = {0,0,0,0};
    const float cexp = 0.18033688011112042f;   // log2(e)/8  (scores = raw/8)

    for (int kt = wave * 2; kt < wave * 2 + 2; kt++) {
        const int key0 = kt * 128;
        const int g0   = key0 >> 4;              // 16-key group base
        const int s0   = key0 >> 5;              // 32-key block base
        const f32x4 z = {0,0,0,0};

        // ---- pair 1: S^T = K·Q^T for q-tiles A,B ----
        f32x4 stA[8], stB[8];
        #pragma unroll
        for (int mt = 0; mt < 8; mt++) {
            bf16x8 k0 = *(const bf16x8*)(kbase + (size_t)((g0 + mt) * 2    ) * 64 * 8);
            bf16x8 k1 = *(const bf16x8*)(kbase + (size_t)((g0 + mt) * 2 + 1) * 64 * 8);
            stA[mt] = MFMA_BF16(k0, qA0, z, 0, 0, 0);
            stA[mt] = MFMA_BF16(k1, qA1, stA[mt], 0, 0, 0);
            stB[mt] = MFMA_BF16(k0, qB0, z, 0, 0, 0);
            stB[mt] = MFMA_BF16(k1, qB1, stB[mt], 0, 0, 0);
        }

        // ---- exp pair 1 -> pt tiles 0,1 (hides pair-2 K load latency) ----
        asm volatile("" ::: "memory");
        #pragma unroll
        for (int mt = 0; mt < 8; mt++) {
            float p0 = __builtin_amdgcn_exp2f(stA[mt][0] * cexp);
            float p1 = __builtin_amdgcn_exp2f(stA[mt][1] * cexp);
            float p2 = __builtin_amdgcn_exp2f(stA[mt][2] * cexp);
            float p3 = __builtin_amdgcn_exp2f(stA[mt][3] * cexp);
            laccA[0] += p0; laccA[1] += p1; laccA[2] += p2; laccA[3] += p3;
            *(uint2*)(ptw + c * 136 + mt * 16 + quad * 4) = pack4_bf16(p0, p1, p2, p3);
        }
        #pragma unroll
        for (int mt = 0; mt < 8; mt++) {
            float p0 = __builtin_amdgcn_exp2f(stB[mt][0] * cexp);
            float p1 = __builtin_amdgcn_exp2f(stB[mt][1] * cexp);
            float p2 = __builtin_amdgcn_exp2f(stB[mt][2] * cexp);
            float p3 = __builtin_amdgcn_exp2f(stB[mt][3] * cexp);
            laccB[0] += p0; laccB[1] += p1; laccB[2] += p2; laccB[3] += p3;
            *(uint2*)(ptw + 2176 + c * 136 + mt * 16 + quad * 4) = pack4_bf16(p0, p1, p2, p3);
        }
        asm volatile("" ::: "memory");

        // ---- pair 2: S^T for q-tiles C,D (K frags re-read, L2-hot) ----
        f32x4 stC[8], stD[8];
        #pragma unroll
        for (int mt = 0; mt < 8; mt++) {
            bf16x8 k0 = *(const bf16x8*)(kbase + (size_t)((g0 + mt) * 2    ) * 64 * 8);
            bf16x8 k1 = *(const bf16x8*)(kbase + (size_t)((g0 + mt) * 2 + 1) * 64 * 8);
            stC[mt] = MFMA_BF16(k0, qC0, z, 0, 0, 0);
            stC[mt] = MFMA_BF16(k1, qC1, stC[mt], 0, 0, 0);
            stD[mt] = MFMA_BF16(k0, qD0, z, 0, 0, 0);
            stD[mt] = MFMA_BF16(k1, qD1, stD[mt], 0, 0, 0);
        }

        // ---- preload V ks=0,1 so latency hides under exp section ----
        bf16x8 va[2][4];
        #pragma unroll
        for (int mt = 0; mt < 4; mt++) {
            va[0][mt] = *(const bf16x8*)(vbase + (size_t)((s0    ) * 4 + mt) * 64 * 8);
            va[1][mt] = *(const bf16x8*)(vbase + (size_t)((s0 + 1) * 4 + mt) * 64 * 8);
        }

        // ---- exp pair 2 -> pt tiles 2,3 ----
        asm volatile("" ::: "memory");
        #pragma unroll
        for (int mt = 0; mt < 8; mt++) {
            float p0 = __builtin_amdgcn_exp2f(stC[mt][0] * cexp);
            float p1 = __builtin_amdgcn_exp2f(stC[mt][1] * cexp);
            float p2 = __builtin_amdgcn_exp2f(stC[mt][2] * cexp);
            float p3 = __builtin_amdgcn_exp2f(stC[mt][3] * cexp);
            laccC[0] += p0; laccC[1] += p1; laccC[2] += p2; laccC[3] += p3;
            *(uint2*)(ptw + 2 * 2176 + c * 136 + mt * 16 + quad * 4) = pack4_bf16(p0, p1, p2, p3);
        }
        #pragma unroll
        for (int mt = 0; mt < 8; mt++) {
            float p0 = __builtin_amdgcn_exp2f(stD[mt][0] * cexp);
            float p1 = __builtin_amdgcn_exp2f(stD[mt][1] * cexp);
            float p2 = __builtin_amdgcn_exp2f(stD[mt][2] * cexp);
            float p3 = __builtin_amdgcn_exp2f(stD[mt][3] * cexp);
            laccD[0] += p0; laccD[1] += p1; laccD[2] += p2; laccD[3] += p3;
            *(uint2*)(ptw + 3 * 2176 + c * 136 + mt * 16 + quad * 4) = pack4_bf16(p0, p1, p2, p3);
        }
        asm volatile("" ::: "memory");

        // ---- O^T += V^T·P^T for all 4 q-tiles; V frags loaded once ----
        #pragma unroll
        for (int ks = 0; ks < 4; ks++) {
            bf16x8 pbA = *(const bf16x8*)(ptw            + c * 136 + ks * 32 + quad * 8);
            bf16x8 pbB = *(const bf16x8*)(ptw +     2176 + c * 136 + ks * 32 + quad * 8);
            bf16x8 pbC = *(const bf16x8*)(ptw + 2 * 2176 + c * 136 + ks * 32 + quad * 8);
            bf16x8 pbD = *(const bf16x8*)(ptw + 3 * 2176 + c * 136 + ks * 32 + quad * 8);
            bf16x8 v0 = va[ks & 1][0], v1 = va[ks & 1][1];
            bf16x8 v2 = va[ks & 1][2], v3 = va[ks & 1][3];
            if (ks < 2) {
                #pragma unroll
                for (int mt = 0; mt < 4; mt++)
                    va[ks & 1][mt] =
                        *(const bf16x8*)(vbase + (size_t)((s0 + ks + 2) * 4 + mt) * 64 * 8);
            }
            oa0 = MFMA_BF16(v0, pbA, oa0, 0, 0, 0);
            oa1 = MFMA_BF16(v1, pbA, oa1, 0, 0, 0);
            oa2 = MFMA_BF16(v2, pbA, oa2, 0, 0, 0);
            oa3 = MFMA_BF16(v3, pbA, oa3, 0, 0, 0);
            ob0 = MFMA_BF16(v0, pbB, ob0, 0, 0, 0);
            ob1 = MFMA_BF16(v1, pbB, ob1, 0, 0, 0);
            ob2 = MFMA_BF16(v2, pbB, ob2, 0, 0, 0);
            ob3 = MFMA_BF16(v3, pbB, ob3, 0, 0, 0);
            oc0 = MFMA_BF16(v0, pbC, oc0, 0, 0, 0);
            oc1 = MFMA_BF16(v1, pbC, oc1, 0, 0, 0);
            oc2 = MFMA_BF16(v2, pbC, oc2, 0, 0, 0);
            oc3 = MFMA_BF16(v3, pbC, oc3, 0, 0, 0);
            od0 = MFMA_BF16(v0, pbD, od0, 0, 0, 0);
            od1 = MFMA_BF16(v1, pbD, od1, 0, 0, 0);
            od2 = MFMA_BF16(v2, pbD, od2, 0, 0, 0);
            od3 = MFMA_BF16(v3, pbD, od3, 0, 0, 0);
        }
        asm volatile("" ::: "memory");
    }

    // ---- one l reduction per wave per q-tile ----
    float lA = (laccA[0] + laccA[1]) + (laccA[2] + laccA[3]);
    lA += __shfl_xor(lA, 16); lA += __shfl_xor(lA, 32);
    float lB = (laccB[0] + laccB[1]) + (laccB[2] + laccB[3]);
    lB += __shfl_xor(lB, 16); lB += __shfl_xor(lB, 32);
    float lC = (laccC[0] + laccC[1]) + (laccC[2] + laccC[3]);
    lC += __shfl_xor(lC, 16); lC += __shfl_xor(lC, 32);
    float lD = (laccD[0] + laccD[1]) + (laccD[2] + laccD[3]);
    lD += __shfl_xor(lD, 16); lD += __shfl_xor(lD, 32);
    if (quad == 0) {
        lbuf[wave][0][c] = lA; lbuf[wave][1][c] = lB;
        lbuf[wave][2][c] = lC; lbuf[wave][3][c] = lD;
    }

    // ---- all waves done with pt before obuf overlays it ----
    __syncthreads();

    // obuf(p,qt,r,d) = obase[((p*4+qt)*16 + r)*68 + d]
    if (wave < 4) {
        float* o0 = obase + ((size_t)(wave * 4 + 0) * 16 + c) * 68 + quad * 4;
        float* o1 = obase + ((size_t)(wave * 4 + 1) * 16 + c) * 68 + quad * 4;
        float* o2 = obase + ((size_t)(wave * 4 + 2) * 16 + c) * 68 + quad * 4;
        float* o3 = obase + ((size_t)(wave * 4 + 3) * 16 + c) * 68 + quad * 4;
        *(f32x4*)(o0 +  0) = oa0; *(f32x4*)(o0 + 16) = oa1;
        *(f32x4*)(o0 + 32) = oa2; *(f32x4*)(o0 + 48) = oa3;
        *(f32x4*)(o1 +  0) = ob0; *(f32x4*)(o1 + 16) = ob1;
        *(f32x4*)(o1 + 32) = ob2; *(f32x4*)(o1 + 48) = ob3;
        *(f32x4*)(o2 +  0) = oc0; *(f32x4*)(o2 + 16) = oc1;
        *(f32x4*)(o2 + 32) = oc2; *(f32x4*)(o2 + 48) = oc3;
        *(f32x4*)(o3 +  0) = od0; *(f32x4*)(o3 + 16) = od1;
        *(f32x4*)(o3 + 32) = od2; *(f32x4*)(o3 + 48) = od3;
    }
    __syncthreads();

    if (wave >= 4) {
        const int p = wave - 4;
        float* o0 = obase + ((size_t)(p * 4 + 0) * 16 + c) * 68 + quad * 4;
        float* o1 = obase + ((size_t)(p * 4 + 1) * 16 + c) * 68 + quad * 4;
        float* o2 = obase + ((size_t)(p * 4 + 2) * 16 + c) * 68 + quad * 4;
        float* o3 = obase + ((size_t)(p * 4 + 3) * 16 + c) * 68 + quad * 4;
        #define ADDSTORE(ptr, off, reg) { f32x4 t = *(f32x4*)((ptr) + (off)); \
            t[0] += reg[0]; t[1] += reg[1]; t[2] += reg[2]; t[3] += reg[3];   \
            *(f32x4*)((ptr) + (off)) = t; }
        ADDSTORE(o0,  0, oa0); ADDSTORE(o0, 16, oa1);
        ADDSTORE(o0, 32, oa2); ADDSTORE(o0, 48, oa3);
        ADDSTORE(o1,  0, ob0); ADDSTORE(o1, 16, ob1);
        ADDSTORE(o1, 32, ob2); ADDSTORE(o1, 48, ob3);
        ADDSTORE(o2,  0, oc0); ADDSTORE(o2, 16, oc1);
        ADDSTORE(o2, 32, oc2); ADDSTORE(o2, 48, oc3);
        ADDSTORE(o3,  0, od0); ADDSTORE(o3, 16, od1);
        ADDSTORE(o3, 32, od2); ADDSTORE(o3, 48, od3);
        #undef ADDSTORE
    }
    __syncthreads();

    // ---- combine 4 partials; 512 thr x 8 floats, coalesced ----
    const int tid = threadIdx.x;
    const int row = tid >> 3;                    // block-local q row (0..63)
    const int d0  = (tid & 7) * 8;               // d base (0..56)
    const int qt  = row >> 4;
    const int r   = row & 15;
    float L = 0.f;
    #pragma unroll
    for (int w = 0; w < 8; w++) L += lbuf[w][qt][r];
    const float rl = 1.f / L;
    f32x4 Oa = {0,0,0,0}, Ob = {0,0,0,0};
    #pragma unroll
    for (int p = 0; p < 4; p++) {
        const float* src = obase + ((size_t)(p * 4 + qt) * 16 + r) * 68 + d0;
        f32x4 a   = *(const f32x4*)(src);
        f32x4 bfr = *(const f32x4*)(src + 4);
        Oa[0] += a[0]; Oa[1] += a[1]; Oa[2] += a[2]; Oa[3] += a[3];
        Ob[0] += bfr[0]; Ob[1] += bfr[1]; Ob[2] += bfr[2]; Ob[3] += bfr[3];
    }
    Oa[0] *= rl; Oa[1] *= rl; Oa[2] *= rl; Oa[3] *= rl;
    Ob[0] *= rl; Ob[1] *= rl; Ob[2] *= rl; Ob[3] *= rl;
    float* op = out + (size_t)(tb + row) * 64 + d0;
    *(f32x4*)op       = Oa;
    *(f32x4*)(op + 4) = Ob;
}

// ---------------------------------------------------------------------------
extern "C" void kernel_launch(void* const* d_in, const int* in_sizes, int n_in,
                              void* d_out, int out_size, void* d_ws, size_t ws_size,
                              hipStream_t stream)
{
    const float* x  = (const float*)d_in[0];
    const float* Wk = (const float*)d_in[1];
    const float* Wq = (const float*)d_in[2];
    const float* Wv = (const float*)d_in[3];
    float* out = (float*)d_out;

    char* ws = (char*)d_ws;
    unsigned short* qg  = (unsigned short*)(ws);                  // 2 MiB
    unsigned short* kg2 = (unsigned short*)(ws + (2u << 20));     // 2 MiB
    unsigned short* vg2 = (unsigned short*)(ws + (4u << 20));     // 2 MiB
    unsigned short* wt2 = (unsigned short*)(ws + (6u << 20));     // 192 KiB

    hipLaunchKernelGGL(wt_kernel,   dim3(48),   dim3(256), 0, stream,
                       Wq, Wk, Wv, wt2);
    hipLaunchKernelGGL(proj_kernel, dim3(256),  dim3(256), 0, stream,
                       x, wt2, qg, kg2, vg2);
    hipLaunchKernelGGL(attn_kernel, dim3(256),  dim3(512), 0, stream,
                       qg, kg2, vg2, out);
}

// Round 4
// 102.281 us; speedup vs baseline: 1.0690x; 1.0395x over previous
//
#include <hip/hip_runtime.h>
#include <hip/hip_bf16.h>
#include <stdint.h>

// ---------------------------------------------------------------------------
// Head: out = softmax((x Wq)(x Wk)^T / 8) (x Wv)
// B=8, T=2048, C=512, D=64.  ALL I/O FP32; internals bf16 MFMA + fp32 accum.
//
// R12: attn critical-path cuts. R11 (proj 64-tok tiles) confirmed -3us.
//  (1) S+exp fused per mt: K loaded ONCE per kt (was twice; 16 L2 loads off
//      the serial path), MFMA/trans/VALU interleaved per-mt, st arrays are
//      per-mt transients (peak VGPR ~150, was ~250).
//  (2) Q pre-scaled by log2(e)/8 in proj (same rounding path as the old
//      fp32 s*cexp) -> exp2 consumes S directly; kills 128 v_mul/kt/wave.
//  (3) l computed by MFMA with a ones-A-fragment in the PV loop (16 extra
//      MFMA/kt) replacing 128 lacc adds/kt AND the shfl_xor reduction;
//      l now uses the same bf16 P as the numerator (consistency win).
// proj otherwise unchanged from R11; wt unchanged.
// Keep: frag-order layouts, no-max softmax, XCD batch swizzle,
// launch_bounds (R3: min-waves=4 caused 96MB scratch spill).
//
// MFMA 16x16x32 bf16 fragment maps (gfx950, m89/m91-verified):
//   A: lane holds A[m=lane&15][k=quad*8+j]   (quad=lane>>4, j=0..7)
//   B: lane holds B[k=quad*8+j][n=lane&15]
//   D: lane holds D[row=quad*4+r][col=lane&15] (r=reg 0..3)
//
// Fragment-order chunk layouts (16B chunks, chunk's 8 elems = j=0..7):
//   xs (LDS): chunk[db*64 + (tok ^ (db&7))] = x[tt*64+tok][db*8+j], db=ks*4+quad
//   wt2: chunk[(((w*4+mt)*16+ks)*4+quad)*16+c] = W_w[ks*32+quad*8+j][mt*16+c]
//   kg2: chunk[b*16384 + ((g*2+h)*4+quad)*16+c] = K[b][g*16+c][h*32+quad*8+j]
//   vg2: chunk[b*16384 + ((s*4+mt)*4+quad)*16+c] = V[b][s*32+quad*8+j][mt*16+c]
// ---------------------------------------------------------------------------

typedef short bf16x8 __attribute__((ext_vector_type(8)));
typedef float f32x4 __attribute__((ext_vector_type(4)));

#define MFMA_BF16 __builtin_amdgcn_mfma_f32_16x16x32_bf16

#define CEXP 0.18033688011112042f   /* log2(e)/8  (scores = raw/8) */

__device__ __forceinline__ unsigned int pk2(float a, float b) {
    __hip_bfloat162 h = __float22bfloat162_rn(float2{a, b});   // v_cvt_pk_bf16_f32
    union { __hip_bfloat162 h; unsigned int u; } r; r.h = h;
    return r.u;
}

__device__ __forceinline__ uint2 pack4_bf16(float a, float b, float c, float d) {
    uint2 r; r.x = pk2(a, b); r.y = pk2(c, d); return r;
}

__device__ __forceinline__ bf16x8 cvt8(f32x4 a, f32x4 b) {
    union { bf16x8 v; unsigned int u[4]; } r;
    r.u[0] = pk2(a[0], a[1]); r.u[1] = pk2(a[2], a[3]);
    r.u[2] = pk2(b[0], b[1]); r.u[3] = pk2(b[2], b[3]);
    return r.v;
}

__device__ __forceinline__ unsigned short bf1(float a) {
    __hip_bfloat16 h = __float2bfloat16(a);
    union { __hip_bfloat16 h; unsigned short u; } r; r.h = h;
    return r.u;
}

// ---------------------------------------------------------------------------
// Kernel 0: weight fragments only (48 blocks). Unchanged.
// ---------------------------------------------------------------------------
__global__ void wt_kernel(const float* __restrict__ Wq,
                          const float* __restrict__ Wk,
                          const float* __restrict__ Wv,
                          unsigned short* __restrict__ wt2)
{
    int id = blockIdx.x * 256 + threadIdx.x;      // 12288 = 3*4*16*4*16
    int c    = id & 15;
    int quad = (id >> 4) & 3;
    int ks   = (id >> 6) & 15;
    int mt   = (id >> 10) & 3;
    int w    = id >> 12;
    const float* src = (w == 0) ? Wq : ((w == 1) ? Wk : Wv);
    const int n  = mt * 16 + c;
    const int k0 = ks * 32 + quad * 8;
    unsigned short* dst = wt2 + (size_t)id * 8;
    #pragma unroll
    for (int j = 0; j < 8; j++)
        dst[j] = bf1(src[(size_t)(k0 + j) * 64 + n]);
}

// ---------------------------------------------------------------------------
// Kernel 1: fused convert + projections, 64-token blocks (R11).
//   Only change: q output pre-scaled by CEXP (fp32 mul before bf16 pack).
// 256 blocks x 256 threads; LDS 64KB -> 2 blocks/CU.
// ---------------------------------------------------------------------------
__global__ __launch_bounds__(256, 1) void proj_kernel(
    const float* __restrict__ x, const unsigned short* __restrict__ wt2,
    unsigned short* __restrict__ qg, unsigned short* __restrict__ kg2,
    unsigned short* __restrict__ vg2)
{
    __shared__ unsigned short xs[32768];          // 64 KiB, 4096 16B chunks

    const int tid  = threadIdx.x;
    const int lane = tid & 63;
    const int wave = tid >> 6;
    const int c    = lane & 15;
    const int quad = lane >> 4;
    const int tt   = blockIdx.x;                  // 64-token tile 0..255
    const int t0   = tt * 64;

    // ---- stage x tile (64 tok x 512 C fp32 = 128KB) -> frag-order LDS ----
    const float* xb = x + (size_t)tt * 32768;
    #pragma unroll
    for (int t = 0; t < 16; t++) {
        int i = t * 256 + tid;                    // float8 index 0..4095
        f32x4 a = *(const f32x4*)(xb + (size_t)i * 8);
        f32x4 b = *(const f32x4*)(xb + (size_t)i * 8 + 4);
        int tok = i >> 6;                         // token_local 0..63
        int db  = i & 63;                         // = ks*4+quad (C block)
        *(bf16x8*)(xs + ((size_t)db * 64 + (tok ^ (db & 7))) * 8) = cvt8(a, b);
    }
    __syncthreads();

    // ---- GEMM: wave owns frags f = wave*3..+2, all 4 token-subtiles ----
    f32x4 acc[3][4];
    #pragma unroll
    for (int r = 0; r < 3; r++)
        #pragma unroll
        for (int st = 0; st < 4; st++) acc[r][st] = f32x4{0.f, 0.f, 0.f, 0.f};

    const int fbase = wave * 3;
    #pragma unroll 2
    for (int ks = 0; ks < 16; ks++) {
        bf16x8 wa[3];
        #pragma unroll
        for (int r = 0; r < 3; r++)
            wa[r] = *(const bf16x8*)(
                wt2 + ((size_t)((fbase + r) * 16 + ks) * 64 + lane) * 8);
        const int sw = c ^ ((ks & 1) * 4 + quad);     // (ks*4+quad)&7
        const unsigned short* xrow = xs + ((size_t)(ks * 4 + quad) * 64 + sw) * 8;
        #pragma unroll
        for (int st = 0; st < 4; st++) {
            bf16x8 xf = *(const bf16x8*)(xrow + (size_t)st * 16 * 8);
            #pragma unroll
            for (int r = 0; r < 3; r++)
                acc[r][st] = MFMA_BF16(wa[r], xf, acc[r][st], 0, 0, 0);
        }
    }

    // ---- epilogue: per-frag, per-subtile store ----
    const int b = t0 >> 11;              // batch (constant per block)

    #pragma unroll
    for (int r = 0; r < 3; r++) {
        const int f  = fbase + r;
        const int w  = f >> 2;           // matrix: 0:q 1:k 2:v
        const int mt = f & 3;
        #pragma unroll
        for (int st = 0; st < 4; st++) {
            const int ts = t0 + st * 16;         // subtile global token base
            const int tb = ts & 2047;            // batch-local tile base
            if (w == 0) {
                // q pre-scaled by CEXP so attn's exp2 consumes S directly
                unsigned short* base = qg + (size_t)(ts + c) * 64;
                *(uint2*)(base + mt * 16 + quad * 4) =
                    pack4_bf16(acc[r][st][0] * CEXP, acc[r][st][1] * CEXP,
                               acc[r][st][2] * CEXP, acc[r][st][3] * CEXP);
            } else if (w == 1) {
                const int g  = tb >> 4;
                const int h  = mt >> 1;
                const int qk = (mt & 1) * 2 + (quad >> 1);
                size_t chunk = (size_t)b * 16384 + ((size_t)(g * 2 + h) * 4 + qk) * 16 + c;
                *(uint2*)(kg2 + chunk * 8 + (quad & 1) * 4) =
                    pack4_bf16(acc[r][st][0], acc[r][st][1], acc[r][st][2], acc[r][st][3]);
            } else {
                const int tk = tb + c;
                const int s  = tk >> 5;
                const int qv = (tk >> 3) & 3;
                const int j  = tk & 7;
                size_t chunk = (size_t)b * 16384 + ((size_t)(s * 4 + mt) * 4 + qv) * 16 + quad * 4;
                unsigned short* dst = vg2 + chunk * 8 + j;
                dst[0]  = bf1(acc[r][st][0]);
                dst[8]  = bf1(acc[r][st][1]);
                dst[16] = bf1(acc[r][st][2]);
                dst[24] = bf1(acc[r][st][3]);
            }
        }
    }
}

// ---------------------------------------------------------------------------
// Kernel 2: flash attention, 64 q-rows per block (4 q-tiles), 8 waves
// splitting the 2048 keys 8 ways. R12 main loop: per mt, {2 K loads ->
// 8 MFMA (4 tiles) -> 16 exp2 -> 4 pt writes}; PV computes l via
// ones-fragment MFMA alongside O. No shfl reduction.
// 256 blocks x 512 threads; LDS ~138KB -> 1 block/CU.
// ---------------------------------------------------------------------------
__global__ __launch_bounds__(512, 2) void attn_kernel(
    const unsigned short* __restrict__ qg, const unsigned short* __restrict__ kg2,
    const unsigned short* __restrict__ vg2, float* __restrict__ out)
{
    // pt: [wave][qtile][q=16][key=136]  (136 stride de-conflicts)
    __shared__ __align__(16) unsigned short pt[8][4][16 * 136];  // 139,264 B
    __shared__ float lbuf[8][4][16];                             // 2 KiB
    // obuf overlays pt AFTER the post-loop barrier: [part=4][qt=4][q=16][d=68]
    float* obase = reinterpret_cast<float*>(&pt[0][0][0]);       // 69,632 B used

    const int lane = threadIdx.x & 63;
    const int wave = threadIdx.x >> 6;           // 0..7
    const int c    = lane & 15;
    const int quad = lane >> 4;
    const int b    = blockIdx.x & 7;             // batch -> XCD (L2 locality)
    const int g    = blockIdx.x >> 3;            // 64-row group (0..31)
    const int tb   = b * 2048 + g * 64;          // block q base

    unsigned short* ptw = &pt[wave][0][0];
    const unsigned short* kbase = kg2 + ((size_t)b * 16384 + lane) * 8;
    const unsigned short* vbase = vg2 + ((size_t)b * 16384 + lane) * 8;

    // Q frags for 4 q-tiles (pre-scaled by CEXP in proj)
    bf16x8 qA0 = *(const bf16x8*)(qg + (size_t)(tb + c) * 64 + quad * 8);
    bf16x8 qA1 = *(const bf16x8*)(qg + (size_t)(tb + c) * 64 + 32 + quad * 8);
    bf16x8 qB0 = *(const bf16x8*)(qg + (size_t)(tb + 16 + c) * 64 + quad * 8);
    bf16x8 qB1 = *(const bf16x8*)(qg + (size_t)(tb + 16 + c) * 64 + 32 + quad * 8);
    bf16x8 qC0 = *(const bf16x8*)(qg + (size_t)(tb + 32 + c) * 64 + quad * 8);
    bf16x8 qC1 = *(const bf16x8*)(qg + (size_t)(tb + 32 + c) * 64 + 32 + quad * 8);
    bf16x8 qD0 = *(const bf16x8*)(qg + (size_t)(tb + 48 + c) * 64 + quad * 8);
    bf16x8 qD1 = *(const bf16x8*)(qg + (size_t)(tb + 48 + c) * 64 + 32 + quad * 8);

    // ones A-fragment for l-by-MFMA (bf16 1.0 = 0x3F80)
    bf16x8 ones;
    #pragma unroll
    for (int j = 0; j < 8; j++) ones[j] = (short)0x3F80;

    f32x4 oa0 = {0,0,0,0}, oa1 = {0,0,0,0}, oa2 = {0,0,0,0}, oa3 = {0,0,0,0};
    f32x4 ob0 = {0,0,0,0}, ob1 = {0,0,0,0}, ob2 = {0,0,0,0}, ob3 = {0,0,0,0};
    f32x4 oc0 = {0,0,0,0}, oc1 = {0,0,0,0}, oc2 = {0,0,0,0}, oc3 = {0,0,0,0};
    f32x4 od0 = {0,0,0,0}, od1 = {0,0,0,0}, od2 = {0,0,0,0}, od3 = {0,0,0,0};
    f32x4 laccA = {0,0,0,0}, laccB = {0,0,0,0};
    f32x4 laccC = {0,0,0,0}, laccD = {0,0,0,0};

    for (int kt = wave * 2; kt < wave * 2 + 2; kt++) {
        const int key0 = kt * 128;
        const int g0   = key0 >> 4;              // 16-key group base
        const int s0   = key0 >> 5;              // 32-key block base
        const f32x4 z = {0,0,0,0};

        // ---- preload V ks=0,1 early; latency hides under S/exp ----
        bf16x8 va[2][4];
        #pragma unroll
        for (int mt = 0; mt < 4; mt++) {
            va[0][mt] = *(const bf16x8*)(vbase + (size_t)((s0    ) * 4 + mt) * 64 * 8);
            va[1][mt] = *(const bf16x8*)(vbase + (size_t)((s0 + 1) * 4 + mt) * 64 * 8);
        }

        // ---- fused S+exp per mt: K loaded once, 8 MFMA + 16 exp2 ----
        #pragma unroll
        for (int mt = 0; mt < 8; mt++) {
            bf16x8 k0 = *(const bf16x8*)(kbase + (size_t)((g0 + mt) * 2    ) * 64 * 8);
            bf16x8 k1 = *(const bf16x8*)(kbase + (size_t)((g0 + mt) * 2 + 1) * 64 * 8);
            f32x4 sA = MFMA_BF16(k0, qA0, z, 0, 0, 0);
            sA = MFMA_BF16(k1, qA1, sA, 0, 0, 0);
            f32x4 sB = MFMA_BF16(k0, qB0, z, 0, 0, 0);
            sB = MFMA_BF16(k1, qB1, sB, 0, 0, 0);
            f32x4 sC = MFMA_BF16(k0, qC0, z, 0, 0, 0);
            sC = MFMA_BF16(k1, qC1, sC, 0, 0, 0);
            f32x4 sD = MFMA_BF16(k0, qD0, z, 0, 0, 0);
            sD = MFMA_BF16(k1, qD1, sD, 0, 0, 0);
            *(uint2*)(ptw            + c * 136 + mt * 16 + quad * 4) =
                pack4_bf16(__builtin_amdgcn_exp2f(sA[0]), __builtin_amdgcn_exp2f(sA[1]),
                           __builtin_amdgcn_exp2f(sA[2]), __builtin_amdgcn_exp2f(sA[3]));
            *(uint2*)(ptw +     2176 + c * 136 + mt * 16 + quad * 4) =
                pack4_bf16(__builtin_amdgcn_exp2f(sB[0]), __builtin_amdgcn_exp2f(sB[1]),
                           __builtin_amdgcn_exp2f(sB[2]), __builtin_amdgcn_exp2f(sB[3]));
            *(uint2*)(ptw + 2 * 2176 + c * 136 + mt * 16 + quad * 4) =
                pack4_bf16(__builtin_amdgcn_exp2f(sC[0]), __builtin_amdgcn_exp2f(sC[1]),
                           __builtin_amdgcn_exp2f(sC[2]), __builtin_amdgcn_exp2f(sC[3]));
            *(uint2*)(ptw + 3 * 2176 + c * 136 + mt * 16 + quad * 4) =
                pack4_bf16(__builtin_amdgcn_exp2f(sD[0]), __builtin_amdgcn_exp2f(sD[1]),
                           __builtin_amdgcn_exp2f(sD[2]), __builtin_amdgcn_exp2f(sD[3]));
        }
        asm volatile("" ::: "memory");

        // ---- O^T += V^T·P^T for 4 q-tiles; l via ones-MFMA ----
        #pragma unroll
        for (int ks = 0; ks < 4; ks++) {
            bf16x8 pbA = *(const bf16x8*)(ptw            + c * 136 + ks * 32 + quad * 8);
            bf16x8 pbB = *(const bf16x8*)(ptw +     2176 + c * 136 + ks * 32 + quad * 8);
            bf16x8 pbC = *(const bf16x8*)(ptw + 2 * 2176 + c * 136 + ks * 32 + quad * 8);
            bf16x8 pbD = *(const bf16x8*)(ptw + 3 * 2176 + c * 136 + ks * 32 + quad * 8);
            bf16x8 v0 = va[ks & 1][0], v1 = va[ks & 1][1];
            bf16x8 v2 = va[ks & 1][2], v3 = va[ks & 1][3];
            if (ks < 2) {
                #pragma unroll
                for (int mt = 0; mt < 4; mt++)
                    va[ks & 1][mt] =
                        *(const bf16x8*)(vbase + (size_t)((s0 + ks + 2) * 4 + mt) * 64 * 8);
            }
            oa0 = MFMA_BF16(v0, pbA, oa0, 0, 0, 0);
            oa1 = MFMA_BF16(v1, pbA, oa1, 0, 0, 0);
            oa2 = MFMA_BF16(v2, pbA, oa2, 0, 0, 0);
            oa3 = MFMA_BF16(v3, pbA, oa3, 0, 0, 0);
            laccA = MFMA_BF16(ones, pbA, laccA, 0, 0, 0);
            ob0 = MFMA_BF16(v0, pbB, ob0, 0, 0, 0);
            ob1 = MFMA_BF16(v1, pbB, ob1, 0, 0, 0);
            ob2 = MFMA_BF16(v2, pbB, ob2, 0, 0, 0);
            ob3 = MFMA_BF16(v3, pbB, ob3, 0, 0, 0);
            laccB = MFMA_BF16(ones, pbB, laccB, 0, 0, 0);
            oc0 = MFMA_BF16(v0, pbC, oc0, 0, 0, 0);
            oc1 = MFMA_BF16(v1, pbC, oc1, 0, 0, 0);
            oc2 = MFMA_BF16(v2, pbC, oc2, 0, 0, 0);
            oc3 = MFMA_BF16(v3, pbC, oc3, 0, 0, 0);
            laccC = MFMA_BF16(ones, pbC, laccC, 0, 0, 0);
            od0 = MFMA_BF16(v0, pbD, od0, 0, 0, 0);
            od1 = MFMA_BF16(v1, pbD, od1, 0, 0, 0);
            od2 = MFMA_BF16(v2, pbD, od2, 0, 0, 0);
            od3 = MFMA_BF16(v3, pbD, od3, 0, 0, 0);
            laccD = MFMA_BF16(ones, pbD, laccD, 0, 0, 0);
        }
        asm volatile("" ::: "memory");
    }

    // ---- l[q=c] sits in lacc*[0] (all D rows identical for ones-A) ----
    if (quad == 0) {
        lbuf[wave][0][c] = laccA[0]; lbuf[wave][1][c] = laccB[0];
        lbuf[wave][2][c] = laccC[0]; lbuf[wave][3][c] = laccD[0];
    }

    // ---- all waves done with pt before obuf overlays it ----
    __syncthreads();

    // obuf(p,qt,r,d) = obase[((p*4+qt)*16 + r)*68 + d]
    if (wave < 4) {
        float* o0 = obase + ((size_t)(wave * 4 + 0) * 16 + c) * 68 + quad * 4;
        float* o1 = obase + ((size_t)(wave * 4 + 1) * 16 + c) * 68 + quad * 4;
        float* o2 = obase + ((size_t)(wave * 4 + 2) * 16 + c) * 68 + quad * 4;
        float* o3 = obase + ((size_t)(wave * 4 + 3) * 16 + c) * 68 + quad * 4;
        *(f32x4*)(o0 +  0) = oa0; *(f32x4*)(o0 + 16) = oa1;
        *(f32x4*)(o0 + 32) = oa2; *(f32x4*)(o0 + 48) = oa3;
        *(f32x4*)(o1 +  0) = ob0; *(f32x4*)(o1 + 16) = ob1;
        *(f32x4*)(o1 + 32) = ob2; *(f32x4*)(o1 + 48) = ob3;
        *(f32x4*)(o2 +  0) = oc0; *(f32x4*)(o2 + 16) = oc1;
        *(f32x4*)(o2 + 32) = oc2; *(f32x4*)(o2 + 48) = oc3;
        *(f32x4*)(o3 +  0) = od0; *(f32x4*)(o3 + 16) = od1;
        *(f32x4*)(o3 + 32) = od2; *(f32x4*)(o3 + 48) = od3;
    }
    __syncthreads();

    if (wave >= 4) {
        const int p = wave - 4;
        float* o0 = obase + ((size_t)(p * 4 + 0) * 16 + c) * 68 + quad * 4;
        float* o1 = obase + ((size_t)(p * 4 + 1) * 16 + c) * 68 + quad * 4;
        float* o2 = obase + ((size_t)(p * 4 + 2) * 16 + c) * 68 + quad * 4;
        float* o3 = obase + ((size_t)(p * 4 + 3) * 16 + c) * 68 + quad * 4;
        #define ADDSTORE(ptr, off, reg) { f32x4 t = *(f32x4*)((ptr) + (off)); \
            t[0] += reg[0]; t[1] += reg[1]; t[2] += reg[2]; t[3] += reg[3];   \
            *(f32x4*)((ptr) + (off)) = t; }
        ADDSTORE(o0,  0, oa0); ADDSTORE(o0, 16, oa1);
        ADDSTORE(o0, 32, oa2); ADDSTORE(o0, 48, oa3);
        ADDSTORE(o1,  0, ob0); ADDSTORE(o1, 16, ob1);
        ADDSTORE(o1, 32, ob2); ADDSTORE(o1, 48, ob3);
        ADDSTORE(o2,  0, oc0); ADDSTORE(o2, 16, oc1);
        ADDSTORE(o2, 32, oc2); ADDSTORE(o2, 48, oc3);
        ADDSTORE(o3,  0, od0); ADDSTORE(o3, 16, od1);
        ADDSTORE(o3, 32, od2); ADDSTORE(o3, 48, od3);
        #undef ADDSTORE
    }
    __syncthreads();

    // ---- combine 4 partials; 512 thr x 8 floats, coalesced ----
    const int tid = threadIdx.x;
    const int row = tid >> 3;                    // block-local q row (0..63)
    const int d0  = (tid & 7) * 8;               // d base (0..56)
    const int qt  = row >> 4;
    const int r   = row & 15;
    float L = 0.f;
    #pragma unroll
    for (int w = 0; w < 8; w++) L += lbuf[w][qt][r];
    const float rl = 1.f / L;
    f32x4 Oa = {0,0,0,0}, Ob = {0,0,0,0};
    #pragma unroll
    for (int p = 0; p < 4; p++) {
        const float* src = obase + ((size_t)(p * 4 + qt) * 16 + r) * 68 + d0;
        f32x4 a   = *(const f32x4*)(src);
        f32x4 bfr = *(const f32x4*)(src + 4);
        Oa[0] += a[0]; Oa[1] += a[1]; Oa[2] += a[2]; Oa[3] += a[3];
        Ob[0] += bfr[0]; Ob[1] += bfr[1]; Ob[2] += bfr[2]; Ob[3] += bfr[3];
    }
    Oa[0] *= rl; Oa[1] *= rl; Oa[2] *= rl; Oa[3] *= rl;
    Ob[0] *= rl; Ob[1] *= rl; Ob[2] *= rl; Ob[3] *= rl;
    float* op = out + (size_t)(tb + row) * 64 + d0;
    *(f32x4*)op       = Oa;
    *(f32x4*)(op + 4) = Ob;
}

// ---------------------------------------------------------------------------
extern "C" void kernel_launch(void* const* d_in, const int* in_sizes, int n_in,
                              void* d_out, int out_size, void* d_ws, size_t ws_size,
                              hipStream_t stream)
{
    const float* x  = (const float*)d_in[0];
    const float* Wk = (const float*)d_in[1];
    const float* Wq = (const float*)d_in[2];
    const float* Wv = (const float*)d_in[3];
    float* out = (float*)d_out;

    char* ws = (char*)d_ws;
    unsigned short* qg  = (unsigned short*)(ws);                  // 2 MiB
    unsigned short* kg2 = (unsigned short*)(ws + (2u << 20));     // 2 MiB
    unsigned short* vg2 = (unsigned short*)(ws + (4u << 20));     // 2 MiB
    unsigned short* wt2 = (unsigned short*)(ws + (6u << 20));     // 192 KiB

    hipLaunchKernelGGL(wt_kernel,   dim3(48),   dim3(256), 0, stream,
                       Wq, Wk, Wv, wt2);
    hipLaunchKernelGGL(proj_kernel, dim3(256),  dim3(256), 0, stream,
                       x, wt2, qg, kg2, vg2);
    hipLaunchKernelGGL(attn_kernel, dim3(256),  dim3(512), 0, stream,
                       qg, kg2, vg2, out);
}